// Round 3
// baseline (174.851 us; speedup 1.0000x reference)
//
#include <hip/hip_runtime.h>
#include <stdint.h>

#define EPSF 1e-8f

using bf16x8 = __attribute__((ext_vector_type(8))) __bf16;
using f32x4  = __attribute__((ext_vector_type(4))) float;

__device__ __forceinline__ unsigned short f32_to_bf16(float f) {
  union { float f; unsigned int u; } v; v.f = f;
  unsigned int r = (v.u + 0x7FFFu + ((v.u >> 16) & 1u)) >> 16;  // RNE
  return (unsigned short)r;
}

__device__ __forceinline__ float wave_sum(float v) {
#pragma unroll
  for (int off = 32; off > 0; off >>= 1) v += __shfl_down(v, off, 64);
  return v;
}

// ---------------- weight ternary quant + per-row scale ----------------
__global__ __launch_bounds__(256) void wquant_kernel(
    const float* __restrict__ w, const float* __restrict__ row_scale,
    unsigned short* __restrict__ wq, float* __restrict__ scale, int K) {
  const int row = blockIdx.x;
  const int t = threadIdx.x;
  const float* wr = w + (size_t)row * K;
  float4 v0 = reinterpret_cast<const float4*>(wr)[2 * t];
  float4 v1 = reinterpret_cast<const float4*>(wr)[2 * t + 1];
  float f[8] = {v0.x, v0.y, v0.z, v0.w, v1.x, v1.y, v1.z, v1.w};
  float sa = 0.f, sq = 0.f;
#pragma unroll
  for (int i = 0; i < 8; ++i) { sa += fabsf(f[i]); sq += f[i] * f[i]; }
  sa = wave_sum(sa);
  sq = wave_sum(sq);
  __shared__ float smA[4], smQ[4];
  const int wid = t >> 6;
  if ((t & 63) == 0) { smA[wid] = sa; smQ[wid] = sq; }
  __syncthreads();
  const float sumabs = smA[0] + smA[1] + smA[2] + smA[3];
  const float sumsq  = smQ[0] + smQ[1] + smQ[2] + smQ[3];
  const float absmean = sumabs / (float)K;
  const float thr = 0.5f * absmean;
  union { unsigned short s[8]; uint4 u; } pk;
#pragma unroll
  for (int i = 0; i < 8; ++i)
    pk.s[i] = (fabsf(f[i]) > thr) ? (f[i] > 0.f ? (unsigned short)0x3F80u
                                                : (unsigned short)0xBF80u)
                                  : (unsigned short)0u;
  reinterpret_cast<uint4*>(wq + (size_t)row * K)[t] = pk.u;
  if (t == 0)
    scale[row] = absmean * rsqrtf(sumsq / (float)K + EPSF) * row_scale[row];
}

// ---------------- input RMSNorm * g -> bf16 ----------------
__global__ __launch_bounds__(256) void xnorm_kernel(
    const float* __restrict__ x, const float* __restrict__ g,
    unsigned short* __restrict__ xn, int K) {
  const int row = blockIdx.x;
  const int t = threadIdx.x;
  const float* xr = x + (size_t)row * K;
  float4 v0 = reinterpret_cast<const float4*>(xr)[2 * t];
  float4 v1 = reinterpret_cast<const float4*>(xr)[2 * t + 1];
  float f[8] = {v0.x, v0.y, v0.z, v0.w, v1.x, v1.y, v1.z, v1.w};
  float sq = 0.f;
#pragma unroll
  for (int i = 0; i < 8; ++i) sq += f[i] * f[i];
  sq = wave_sum(sq);
  __shared__ float smQ[4];
  const int wid = t >> 6;
  if ((t & 63) == 0) smQ[wid] = sq;
  __syncthreads();
  const float sumsq = smQ[0] + smQ[1] + smQ[2] + smQ[3];
  const float rs = rsqrtf(sumsq / (float)K + EPSF);
  float4 g0 = reinterpret_cast<const float4*>(g)[2 * t];
  float4 g1 = reinterpret_cast<const float4*>(g)[2 * t + 1];
  float gg[8] = {g0.x, g0.y, g0.z, g0.w, g1.x, g1.y, g1.z, g1.w};
  union { unsigned short s[8]; uint4 u; } pk;
#pragma unroll
  for (int i = 0; i < 8; ++i) pk.s[i] = f32_to_bf16(f[i] * rs * gg[i]);
  reinterpret_cast<uint4*>(xn + (size_t)row * K)[t] = pk.u;
}

// ---------------- bf16 NT GEMM, 256x256 tile, 8-phase pipeline ----------------
// C[m,n] = scale[n]*sum_k A[m,k]*B[n,k] + bias[n]
// 512 threads = 8 waves (2M x 4N); per-wave 128x64 out; BK=64.
// Changes vs round 2:
//  * bn = XCD id (blockIdx&7) when N/256==8: each XCD's L2 pins one 1 MB
//    B-panel for the whole kernel; A panels (no cross-bm reuse) stream and
//    hit L3 (all XCDs advance bm ~in lockstep).
//  * peeled last iteration: no prefetch stages; quadrant stores issued
//    immediately after each quadrant's final MFMA (P5..P8) so the epilogue
//    overlaps the remaining MFMA phases. Counted waits re-derived for peel:
//    VM(6)@P1, VM(4)@P4, VM(0)@P5.
// Steady-state vmcnt FIFO (stage units; 1 stage = 2 gload insts):
//  entry: {S5,S6,S7,S8}(j-1). P1 +S1, VM(6)->drains (j-1)S5,S6 (read P2/P3).
//  P4 +S2..S4, VM(8)->drains (j-1)S7,S8 (read P5). P5 +S5, VM(6)->drains
//  S1,S2 (read P6/P7). P8 +S6..S8, VM(8)->drains S3,S4 (read (j+1).P1).

#define BAR() do { __builtin_amdgcn_sched_barrier(0); \
                   asm volatile("" ::: "memory"); \
                   __builtin_amdgcn_s_barrier(); \
                   asm volatile("" ::: "memory"); \
                   __builtin_amdgcn_sched_barrier(0); } while (0)
#define VM(n) asm volatile("s_waitcnt vmcnt(" #n ")" ::: "memory")

__global__ __launch_bounds__(512, 2) void gemm_kernel(
    const unsigned short* __restrict__ A,   // [M][K] bf16 (xn)
    const unsigned short* __restrict__ B,   // [N][K] bf16 ternary (wq)
    const float* __restrict__ scale, const float* __restrict__ bias,
    float* __restrict__ C, int M, int N, int K) {
  __shared__ unsigned short lds[2][2][2][8192];

  const int tid  = threadIdx.x;
  const int lane = tid & 63;
  const int wid  = tid >> 6;
  const int wm   = wid >> 2;   // 0..1
  const int wn   = wid & 3;    // 0..3
  const int fr   = lane & 15;
  const int kq   = lane >> 4;

  const int NBN = N >> 8;
  int bm, bn;
  if (NBN == 8) {
    // bn-per-XCD: co-resident blocks on an XCD share the B panel (L2-pinned)
    bn = blockIdx.x & 7;
    bm = blockIdx.x >> 3;
  } else {
    const int nwg = gridDim.x;
    const int cpx = nwg >> 3;
    const int swz = (blockIdx.x & 7) * cpx + (blockIdx.x >> 3);
    bn = swz % NBN;
    bm = swz / NBN;
  }
  const int mBase = bm * 256, nBase = bn * 256;

  const size_t K2 = (size_t)K * 2;

  // ---- staging per-thread constants (pre-swizzled source col) ----
  const int srow = tid >> 3;                                   // 0..63
  const int scolswz = ((tid & 7) ^ (srow & 7)) << 4;           // byte
  const char* Abyte = (const char*)A + (size_t)(mBase + srow) * K2 + scolswz;
  const char* Bbyte = (const char*)B +
      (size_t)(nBase + ((srow >> 5) * 64) + (srow & 31)) * K2 + scolswz;

#define STAGE_A(bufi, h, t) do { \
    __builtin_amdgcn_global_load_lds( \
      (const __attribute__((address_space(1))) void*)(Abyte + (size_t)((h) * 64) * K2 + (size_t)(t) * 128), \
      (__attribute__((address_space(3))) void*)(&lds[bufi][0][h][tid * 8]), 16, 0, 0); \
    __builtin_amdgcn_global_load_lds( \
      (const __attribute__((address_space(1))) void*)(Abyte + (size_t)(128 + (h) * 64) * K2 + (size_t)(t) * 128), \
      (__attribute__((address_space(3))) void*)(&lds[bufi][0][h][4096 + tid * 8]), 16, 0, 0); \
  } while (0)

#define STAGE_B(bufi, h, t) do { \
    __builtin_amdgcn_global_load_lds( \
      (const __attribute__((address_space(1))) void*)(Bbyte + (size_t)((h) * 32) * K2 + (size_t)(t) * 128), \
      (__attribute__((address_space(3))) void*)(&lds[bufi][1][h][tid * 8]), 16, 0, 0); \
    __builtin_amdgcn_global_load_lds( \
      (const __attribute__((address_space(1))) void*)(Bbyte + (size_t)(128 + (h) * 32) * K2 + (size_t)(t) * 128), \
      (__attribute__((address_space(3))) void*)(&lds[bufi][1][h][4096 + tid * 8]), 16, 0, 0); \
  } while (0)

  // ---- ds_read per-thread constants (swizzled read col) ----
  const int cbi0 = ((kq ^ (fr & 7)) << 3);        // elem offset, kk=0
  const int cbi1 = (((4 ^ kq) ^ (fr & 7)) << 3);  // elem offset, kk=1
  const int aRow = (wm * 64 + fr) * 64;
  const int bRow = (wn * 32 + fr) * 64;

  bf16x8 aF[4][2], bF[4][2];
  f32x4 acc[8][4];
#pragma unroll
  for (int m = 0; m < 8; ++m)
#pragma unroll
    for (int n = 0; n < 4; ++n) acc[m][n] = (f32x4){0.f, 0.f, 0.f, 0.f};

#define LDA(bufi, mg) do { \
    _Pragma("unroll") for (int mm = 0; mm < 4; ++mm) { \
      aF[mm][0] = *(const bf16x8*)&lds[bufi][0][mg][aRow + mm * 1024 + cbi0]; \
      aF[mm][1] = *(const bf16x8*)&lds[bufi][0][mg][aRow + mm * 1024 + cbi1]; \
    } } while (0)

#define LDB(bufi, np) do { \
    _Pragma("unroll") for (int nn = 0; nn < 2; ++nn) { \
      bF[(np) * 2 + nn][0] = *(const bf16x8*)&lds[bufi][1][np][bRow + nn * 1024 + cbi0]; \
      bF[(np) * 2 + nn][1] = *(const bf16x8*)&lds[bufi][1][np][bRow + nn * 1024 + cbi1]; \
    } } while (0)

#define MFMA_Q(mg, np) do { \
    __builtin_amdgcn_s_setprio(1); \
    _Pragma("unroll") for (int mm = 0; mm < 4; ++mm) \
    _Pragma("unroll") for (int nn = 0; nn < 2; ++nn) { \
      f32x4 c = acc[(mg) * 4 + mm][(np) * 2 + nn]; \
      c = __builtin_amdgcn_mfma_f32_16x16x32_bf16(aF[mm][0], bF[(np) * 2 + nn][0], c, 0, 0, 0); \
      c = __builtin_amdgcn_mfma_f32_16x16x32_bf16(aF[mm][1], bF[(np) * 2 + nn][1], c, 0, 0, 0); \
      acc[(mg) * 4 + mm][(np) * 2 + nn] = c; \
    } \
    __builtin_amdgcn_s_setprio(0); } while (0)

  const int crowBase = mBase + wm * 128 + kq * 4;
  const int ccolBase = nBase + wn * 64 + fr;

#define STORE_Q(mg, np) do { \
    _Pragma("unroll") for (int nn = 0; nn < 2; ++nn) { \
      const int gc = ccolBase + ((np) * 2 + nn) * 16; \
      const float sc = scale[gc]; \
      const float bi = bias[gc]; \
      _Pragma("unroll") for (int mm = 0; mm < 4; ++mm) { \
        const int r0 = crowBase + ((mg) * 4 + mm) * 16; \
        _Pragma("unroll") for (int r = 0; r < 4; ++r) \
          C[(size_t)(r0 + r) * (size_t)N + (size_t)gc] = \
              acc[(mg) * 4 + mm][(np) * 2 + nn][r] * sc + bi; \
      } } } while (0)

  // ---- prologue: tile0 complete, tile1 h0 halves ----
  STAGE_A(0, 0, 0); STAGE_B(0, 0, 0);
  STAGE_A(0, 1, 0); STAGE_B(0, 1, 0);
  STAGE_A(1, 0, 1); STAGE_B(1, 0, 1);
  VM(8);
  BAR();

  const int NT = K >> 6;  // 2048/64 = 32 K-tiles; main loop 15 iters + peel
  for (int i = 0; i < (NT >> 1) - 1; ++i) {
    const int t1  = 2 * i + 1;
    const int tn0 = 2 * i + 2;
    const int tn1 = 2 * i + 3;
    // P1
    LDA(0, 0); LDB(0, 0); STAGE_A(1, 1, t1); VM(6);
    BAR(); MFMA_Q(0, 0); BAR();
    // P2
    LDB(0, 1); STAGE_B(1, 1, t1);
    BAR(); MFMA_Q(0, 1); BAR();
    // P3
    LDA(0, 1); STAGE_A(0, 0, tn0);
    BAR(); MFMA_Q(1, 0); BAR();
    // P4
    STAGE_B(0, 0, tn0); VM(8);
    BAR(); MFMA_Q(1, 1); BAR();
    // P5
    LDA(1, 0); LDB(1, 0); STAGE_A(0, 1, tn0); VM(6);
    BAR(); MFMA_Q(0, 0); BAR();
    // P6
    LDB(1, 1); STAGE_B(0, 1, tn0);
    BAR(); MFMA_Q(0, 1); BAR();
    // P7
    LDA(1, 1); STAGE_A(1, 0, tn1);
    BAR(); MFMA_Q(1, 0); BAR();
    // P8
    STAGE_B(1, 0, tn1); VM(8);
    BAR(); MFMA_Q(1, 1); BAR();
  }

  // ---- peeled last iteration (tiles NT-2 in buf0, NT-1 in buf1) ----
  // Entry outstanding: {A0h1,B0h1,A1h0,B1h0} of the final tiles.
  {
    const int tl = NT - 1;
    // P1: stage buf1 h1 (tile NT-1) — still needed by P6/P7
    LDA(0, 0); LDB(0, 0); STAGE_A(1, 1, tl); VM(6);
    BAR(); MFMA_Q(0, 0); BAR();
    // P2
    LDB(0, 1); STAGE_B(1, 1, tl);
    BAR(); MFMA_Q(0, 1); BAR();
    // P3
    LDA(0, 1);
    BAR(); MFMA_Q(1, 0); BAR();
    // P4: drain buf1 h0 (A1h0,B1h0) -> 2 stages left (peel's S1p,S2p)
    VM(4);
    BAR(); MFMA_Q(1, 1); BAR();
    // P5: drain peel stages; quadrants final from here on -> store each
    LDA(1, 0); LDB(1, 0); VM(0);
    BAR(); MFMA_Q(0, 0); STORE_Q(0, 0); BAR();
    // P6
    LDB(1, 1);
    BAR(); MFMA_Q(0, 1); STORE_Q(0, 1); BAR();
    // P7
    LDA(1, 1);
    BAR(); MFMA_Q(1, 0); STORE_Q(1, 0); BAR();
    // P8
    MFMA_Q(1, 1); STORE_Q(1, 1);
  }
#undef STAGE_A
#undef STAGE_B
#undef LDA
#undef LDB
#undef MFMA_Q
#undef STORE_Q
}

extern "C" void kernel_launch(void* const* d_in, const int* in_sizes, int n_in,
                              void* d_out, int out_size, void* d_ws, size_t ws_size,
                              hipStream_t stream) {
  const float* x         = (const float*)d_in[0];  // [B,S,Din]
  const float* weight    = (const float*)d_in[1];  // [Dout,Din]
  const float* row_scale = (const float*)d_in[2];  // [Dout,1]
  const float* bias      = (const float*)d_in[3];  // [Dout]
  const float* g         = (const float*)d_in[4];  // [Din]
  float* out = (float*)d_out;

  const int Din  = in_sizes[4];         // 2048
  const int Dout = in_sizes[3];         // 2048
  const int Mrows = in_sizes[0] / Din;  // 16384

  char* ws = (char*)d_ws;
  unsigned short* wq = (unsigned short*)ws;
  unsigned short* xn = (unsigned short*)(ws + (size_t)Dout * Din * 2);
  float* scale = (float*)(ws + (size_t)Dout * Din * 2 + (size_t)Mrows * Din * 2);

  wquant_kernel<<<Dout, 256, 0, stream>>>(weight, row_scale, wq, scale, Din);
  xnorm_kernel<<<Mrows, 256, 0, stream>>>(x, g, xn, Din);
  const int grid = (Mrows / 256) * (Dout / 256);
  gemm_kernel<<<grid, 512, 0, stream>>>(xn, wq, scale, bias, out,
                                        Mrows, Dout, Din);
}

// Round 5
// 124.438 us; speedup vs baseline: 1.4051x; 1.4051x over previous
//
#include <hip/hip_runtime.h>
#include <stdint.h>

#define EPSF 1e-8f

using i32x4 = __attribute__((ext_vector_type(4))) int;

__device__ __forceinline__ float wave_sum(float v) {
#pragma unroll
  for (int off = 32; off > 0; off >>= 1) v += __shfl_down(v, off, 64);
  return v;
}
__device__ __forceinline__ float wave_max(float v) {
#pragma unroll
  for (int off = 32; off > 0; off >>= 1) v = fmaxf(v, __shfl_down(v, off, 64));
  return v;
}

// ---------------- weight ternary quant (i8) + per-row scale ----------------
// mask |w|>0.5*mean|w| invariant to row RMSNorm; ternary {-1,0,1} exact in i8.
// scale[o] = mean|w| * rsqrt(mean(w^2)+EPS) * row_scale[o]
__global__ __launch_bounds__(256) void wquant_kernel(
    const float* __restrict__ w, const float* __restrict__ row_scale,
    signed char* __restrict__ wq, float* __restrict__ scale, int K) {
  const int row = blockIdx.x;
  const int t = threadIdx.x;
  const float* wr = w + (size_t)row * K;
  float4 v0 = reinterpret_cast<const float4*>(wr)[2 * t];
  float4 v1 = reinterpret_cast<const float4*>(wr)[2 * t + 1];
  float f[8] = {v0.x, v0.y, v0.z, v0.w, v1.x, v1.y, v1.z, v1.w};
  float sa = 0.f, sq = 0.f;
#pragma unroll
  for (int i = 0; i < 8; ++i) { sa += fabsf(f[i]); sq += f[i] * f[i]; }
  sa = wave_sum(sa);
  sq = wave_sum(sq);
  __shared__ float smA[4], smQ[4];
  const int wid = t >> 6;
  if ((t & 63) == 0) { smA[wid] = sa; smQ[wid] = sq; }
  __syncthreads();
  const float sumabs = smA[0] + smA[1] + smA[2] + smA[3];
  const float sumsq  = smQ[0] + smQ[1] + smQ[2] + smQ[3];
  const float absmean = sumabs / (float)K;
  const float thr = 0.5f * absmean;
  union { signed char c[8]; uint2 u; } pk;
#pragma unroll
  for (int i = 0; i < 8; ++i)
    pk.c[i] = (fabsf(f[i]) > thr) ? (f[i] > 0.f ? (signed char)1 : (signed char)-1)
                                  : (signed char)0;
  reinterpret_cast<uint2*>(wq + (size_t)row * K)[t] = pk.u;
  if (t == 0)
    scale[row] = absmean * rsqrtf(sumsq / (float)K + EPSF) * row_scale[row];
}

// ---------------- input RMSNorm * g -> i8 (per-row symmetric) ----------------
__global__ __launch_bounds__(256) void xnorm_kernel(
    const float* __restrict__ x, const float* __restrict__ g,
    signed char* __restrict__ xq, float* __restrict__ sx, int K) {
  const int row = blockIdx.x;
  const int t = threadIdx.x;
  const float* xr = x + (size_t)row * K;
  float4 v0 = reinterpret_cast<const float4*>(xr)[2 * t];
  float4 v1 = reinterpret_cast<const float4*>(xr)[2 * t + 1];
  float f[8] = {v0.x, v0.y, v0.z, v0.w, v1.x, v1.y, v1.z, v1.w};
  float sq = 0.f;
#pragma unroll
  for (int i = 0; i < 8; ++i) sq += f[i] * f[i];
  sq = wave_sum(sq);
  __shared__ float smQ[4], smM[4];
  const int wid = t >> 6;
  if ((t & 63) == 0) smQ[wid] = sq;
  __syncthreads();
  const float sumsq = smQ[0] + smQ[1] + smQ[2] + smQ[3];
  const float rs = rsqrtf(sumsq / (float)K + EPSF);
  float4 g0 = reinterpret_cast<const float4*>(g)[2 * t];
  float4 g1 = reinterpret_cast<const float4*>(g)[2 * t + 1];
  float gg[8] = {g0.x, g0.y, g0.z, g0.w, g1.x, g1.y, g1.z, g1.w};
  float vv[8]; float am = 0.f;
#pragma unroll
  for (int i = 0; i < 8; ++i) {
    vv[i] = f[i] * rs * gg[i];
    am = fmaxf(am, fabsf(vv[i]));
  }
  am = wave_max(am);
  if ((t & 63) == 0) smM[wid] = am;
  __syncthreads();
  const float amax = fmaxf(fmaxf(smM[0], smM[1]), fmaxf(smM[2], smM[3]));
  const float inv = amax > 0.f ? 127.f / amax : 0.f;
  union { signed char c[8]; uint2 u; } pk;
#pragma unroll
  for (int i = 0; i < 8; ++i)
    pk.c[i] = (signed char)__float2int_rn(vv[i] * inv);
  reinterpret_cast<uint2*>(xq + (size_t)row * K)[t] = pk.u;
  if (t == 0) sx[row] = amax > 0.f ? amax / 127.f : 0.f;
}

// ---------------- i8 NT GEMM, 256x256 tile, 8-phase pipeline ----------------
// C[m,n] = sx[m]*scale[n]*sum_k qA[m,k]*t[n,k] + bias[n]; i32 dot is exact.
// 512 threads = 8 waves (2M x 4N); per-wave 128x64; BK=128 i8 (same byte
// geometry as round-2 bf16 BK=64: stage = 2x16B loads, LDS 128 KiB, same
// counted-vmcnt schedule).
// ROUND-5 FIX vs round 4: bF must hold BOTH B halves (bF[4][2], indexed by
// np*2+nn) — P3/P7 run MFMA_Q(1,0) which consumes B half 0 loaded back at
// P1/P5; round 4's bF[2][2] fed them half-1 data (absmax 279).
// i8 fragment-layout note: any unknown k-permutation within the 16 B/lane
// cancels because A and B fragments use the identical (lane,byte)->k map
// and we feed both operands with the same placement.
// LDS rows are 128 B = 8 granules of 16 B. Additive swizzle
//   c'(r,g) = (g + r + (r>>3)) & 7
// applied as inverse perm on the GLOBAL source granule + forward perm on
// ds_read (both-sides-or-neither; LDS writes stay linear for global_load_lds).
// XCD swizzle: round-2 chunked mapping (round 3's bn-per-XCD raised FETCH
// 2.8x: the 8 blocks sharing an A panel landed on 8 different XCDs).

#define BAR() do { __builtin_amdgcn_sched_barrier(0); \
                   asm volatile("" ::: "memory"); \
                   __builtin_amdgcn_s_barrier(); \
                   asm volatile("" ::: "memory"); \
                   __builtin_amdgcn_sched_barrier(0); } while (0)
#define VM(n) asm volatile("s_waitcnt vmcnt(" #n ")" ::: "memory")

__global__ __launch_bounds__(512, 2) void gemm_kernel(
    const signed char* __restrict__ A,   // [M][K] i8 (xq)
    const signed char* __restrict__ B,   // [N][K] i8 ternary (wq)
    const float* __restrict__ scale, const float* __restrict__ bias,
    const float* __restrict__ sx,
    float* __restrict__ C, int M, int N, int K) {
  __shared__ signed char lds[2][2][2][16384];

  const int tid  = threadIdx.x;
  const int lane = tid & 63;
  const int wid  = tid >> 6;
  const int wm   = wid >> 2;   // 0..1
  const int wn   = wid & 3;    // 0..3
  const int fr   = lane & 15;
  const int kq   = lane >> 4;

  // chunked XCD swizzle (round-2 mapping: all 8 bn co-resident per XCD)
  const int nwg = gridDim.x;
  const int cpx = nwg >> 3;
  const int swz = (blockIdx.x & 7) * cpx + (blockIdx.x >> 3);
  const int NBN = N >> 8;
  const int bn = swz % NBN;
  const int bm = swz / NBN;
  const int mBase = bm * 256, nBase = bn * 256;

  const size_t Kb = (size_t)K;  // bytes per row (i8)

  // ---- staging constants: thread t -> lds row sr=t>>3, granule slot t&7;
  // source granule = inverse perm (same value for the +64-row second load
  // since 64 + (64>>3) = 72 ≡ 0 mod 8).
  const int sr = tid >> 3;                                // 0..63
  const int gsrc = ((tid & 7) - sr - (sr >> 3)) & 7;      // global granule
  const char* Abyte = (const char*)A + (size_t)(mBase + sr) * Kb + gsrc * 16;
  const char* Bbyte = (const char*)B +
      (size_t)(nBase + ((sr >> 5) * 64) + (sr & 31)) * Kb + gsrc * 16;

#define STAGE_A(bufi, h, t) do { \
    __builtin_amdgcn_global_load_lds( \
      (const __attribute__((address_space(1))) void*)(Abyte + (size_t)((h) * 64) * Kb + (size_t)(t) * 128), \
      (__attribute__((address_space(3))) void*)(&lds[bufi][0][h][tid * 16]), 16, 0, 0); \
    __builtin_amdgcn_global_load_lds( \
      (const __attribute__((address_space(1))) void*)(Abyte + (size_t)(128 + (h) * 64) * Kb + (size_t)(t) * 128), \
      (__attribute__((address_space(3))) void*)(&lds[bufi][0][h][8192 + tid * 16]), 16, 0, 0); \
  } while (0)

#define STAGE_B(bufi, h, t) do { \
    __builtin_amdgcn_global_load_lds( \
      (const __attribute__((address_space(1))) void*)(Bbyte + (size_t)((h) * 32) * Kb + (size_t)(t) * 128), \
      (__attribute__((address_space(3))) void*)(&lds[bufi][1][h][tid * 16]), 16, 0, 0); \
    __builtin_amdgcn_global_load_lds( \
      (const __attribute__((address_space(1))) void*)(Bbyte + (size_t)(128 + (h) * 32) * Kb + (size_t)(t) * 128), \
      (__attribute__((address_space(3))) void*)(&lds[bufi][1][h][8192 + tid * 16]), 16, 0, 0); \
  } while (0)

  // ---- reader constants (forward perm on ds_read) ----
  const int raBase = wm * 64 + fr;            // A lds row base (0..127)
  const int rbBase = wn * 32 + fr;            // B lds row base (0..127)
  const int pA = (raBase + (raBase >> 3)) & 7;
  const int pB = (rbBase + (rbBase >> 3)) & 7;

  i32x4 aF[4][2], bF[4][2];
  i32x4 acc[8][4];
#pragma unroll
  for (int m = 0; m < 8; ++m)
#pragma unroll
    for (int n = 0; n < 4; ++n) acc[m][n] = (i32x4){0, 0, 0, 0};

#define LDA(bufi, mg) do { \
    _Pragma("unroll") for (int mm = 0; mm < 4; ++mm) \
    _Pragma("unroll") for (int s = 0; s < 2; ++s) \
      aF[mm][s] = *(const i32x4*)&lds[bufi][0][mg][ \
          (raBase + mm * 16) * 128 + (((s * 4 + kq) + pA + 2 * mm) & 7) * 16]; \
  } while (0)

#define LDB(bufi, np) do { \
    _Pragma("unroll") for (int nn = 0; nn < 2; ++nn) \
    _Pragma("unroll") for (int s = 0; s < 2; ++s) \
      bF[(np) * 2 + nn][s] = *(const i32x4*)&lds[bufi][1][np][ \
          (rbBase + nn * 16) * 128 + (((s * 4 + kq) + pB + 2 * nn) & 7) * 16]; \
  } while (0)

#define MFMA_Q(mg, np) do { \
    __builtin_amdgcn_s_setprio(1); \
    _Pragma("unroll") for (int mm = 0; mm < 4; ++mm) \
    _Pragma("unroll") for (int nn = 0; nn < 2; ++nn) { \
      i32x4 c = acc[(mg) * 4 + mm][(np) * 2 + nn]; \
      c = __builtin_amdgcn_mfma_i32_16x16x64_i8(aF[mm][0], bF[(np) * 2 + nn][0], c, 0, 0, 0); \
      c = __builtin_amdgcn_mfma_i32_16x16x64_i8(aF[mm][1], bF[(np) * 2 + nn][1], c, 0, 0, 0); \
      acc[(mg) * 4 + mm][(np) * 2 + nn] = c; \
    } \
    __builtin_amdgcn_s_setprio(0); } while (0)

  const int crowBase = mBase + wm * 128 + kq * 4;
  const int ccolBase = nBase + wn * 64 + fr;

#define STORE_Q(mg, np) do { \
    float sxq_[4][4]; \
    _Pragma("unroll") for (int mm = 0; mm < 4; ++mm) \
    _Pragma("unroll") for (int r = 0; r < 4; ++r) \
      sxq_[mm][r] = sx[crowBase + ((mg) * 4 + mm) * 16 + r]; \
    _Pragma("unroll") for (int nn = 0; nn < 2; ++nn) { \
      const int gc = ccolBase + ((np) * 2 + nn) * 16; \
      const float sc = scale[gc]; \
      const float bi = bias[gc]; \
      _Pragma("unroll") for (int mm = 0; mm < 4; ++mm) { \
        const int r0 = crowBase + ((mg) * 4 + mm) * 16; \
        _Pragma("unroll") for (int r = 0; r < 4; ++r) \
          C[(size_t)(r0 + r) * (size_t)N + (size_t)gc] = \
              (float)acc[(mg) * 4 + mm][(np) * 2 + nn][r] * (sxq_[mm][r] * sc) + bi; \
      } } } while (0)

  // ---- prologue: tile0 complete, tile1 h0 halves ----
  STAGE_A(0, 0, 0); STAGE_B(0, 0, 0);
  STAGE_A(0, 1, 0); STAGE_B(0, 1, 0);
  STAGE_A(1, 0, 1); STAGE_B(1, 0, 1);
  VM(8);
  BAR();

  const int NT = K >> 7;  // 128-wide K-tiles; 2048/128 = 16; 7 iters + peel
  for (int i = 0; i < (NT >> 1) - 1; ++i) {
    const int t1  = 2 * i + 1;
    const int tn0 = 2 * i + 2;
    const int tn1 = 2 * i + 3;
    // P1
    LDA(0, 0); LDB(0, 0); STAGE_A(1, 1, t1); VM(6);
    BAR(); MFMA_Q(0, 0); BAR();
    // P2
    LDB(0, 1); STAGE_B(1, 1, t1);
    BAR(); MFMA_Q(0, 1); BAR();
    // P3
    LDA(0, 1); STAGE_A(0, 0, tn0);
    BAR(); MFMA_Q(1, 0); BAR();
    // P4
    STAGE_B(0, 0, tn0); VM(8);
    BAR(); MFMA_Q(1, 1); BAR();
    // P5
    LDA(1, 0); LDB(1, 0); STAGE_A(0, 1, tn0); VM(6);
    BAR(); MFMA_Q(0, 0); BAR();
    // P6
    LDB(1, 1); STAGE_B(0, 1, tn0);
    BAR(); MFMA_Q(0, 1); BAR();
    // P7
    LDA(1, 1); STAGE_A(1, 0, tn1);
    BAR(); MFMA_Q(1, 0); BAR();
    // P8
    STAGE_B(1, 0, tn1); VM(8);
    BAR(); MFMA_Q(1, 1); BAR();
  }

  // ---- peeled last iteration (tiles NT-2 in buf0, NT-1 in buf1) ----
  {
    const int tl = NT - 1;
    // P1: stage buf1 h1 (still needed by P6/P7)
    LDA(0, 0); LDB(0, 0); STAGE_A(1, 1, tl); VM(6);
    BAR(); MFMA_Q(0, 0); BAR();
    // P2
    LDB(0, 1); STAGE_B(1, 1, tl);
    BAR(); MFMA_Q(0, 1); BAR();
    // P3
    LDA(0, 1);
    BAR(); MFMA_Q(1, 0); BAR();
    // P4: drain buf1 h0 pair -> 2 stages left
    VM(4);
    BAR(); MFMA_Q(1, 1); BAR();
    // P5: drain remaining; quadrants final from here -> store inline
    LDA(1, 0); LDB(1, 0); VM(0);
    BAR(); MFMA_Q(0, 0); STORE_Q(0, 0); BAR();
    // P6
    LDB(1, 1);
    BAR(); MFMA_Q(0, 1); STORE_Q(0, 1); BAR();
    // P7
    LDA(1, 1);
    BAR(); MFMA_Q(1, 0); STORE_Q(1, 0); BAR();
    // P8
    MFMA_Q(1, 1); STORE_Q(1, 1);
  }
#undef STAGE_A
#undef STAGE_B
#undef LDA
#undef LDB
#undef MFMA_Q
#undef STORE_Q
}

extern "C" void kernel_launch(void* const* d_in, const int* in_sizes, int n_in,
                              void* d_out, int out_size, void* d_ws, size_t ws_size,
                              hipStream_t stream) {
  const float* x         = (const float*)d_in[0];  // [B,S,Din]
  const float* weight    = (const float*)d_in[1];  // [Dout,Din]
  const float* row_scale = (const float*)d_in[2];  // [Dout,1]
  const float* bias      = (const float*)d_in[3];  // [Dout]
  const float* g         = (const float*)d_in[4];  // [Din]
  float* out = (float*)d_out;

  const int Din  = in_sizes[4];         // 2048
  const int Dout = in_sizes[3];         // 2048
  const int Mrows = in_sizes[0] / Din;  // 16384

  // ws: wq i8 [Dout*Din] | xq i8 [M*Din] | scale f32 [Dout] | sx f32 [M]
  char* ws = (char*)d_ws;
  signed char* wq = (signed char*)ws;
  signed char* xq = (signed char*)(ws + (size_t)Dout * Din);
  float* scale = (float*)(ws + (size_t)Dout * Din + (size_t)Mrows * Din);
  float* sx = scale + Dout;

  wquant_kernel<<<Dout, 256, 0, stream>>>(weight, row_scale, wq, scale, Din);
  xnorm_kernel<<<Mrows, 256, 0, stream>>>(x, g, xq, sx, Din);
  const int grid = (Mrows / 256) * (Dout / 256);
  gemm_kernel<<<grid, 512, 0, stream>>>(xq, wq, scale, bias, sx, out,
                                        Mrows, Dout, Din);
}

// Round 6
// 114.248 us; speedup vs baseline: 1.5304x; 1.0892x over previous
//
#include <hip/hip_runtime.h>
#include <stdint.h>

#define EPSF 1e-8f

using i32x4 = __attribute__((ext_vector_type(4))) int;

__device__ __forceinline__ float wave_sum(float v) {
#pragma unroll
  for (int off = 32; off > 0; off >>= 1) v += __shfl_down(v, off, 64);
  return v;
}
__device__ __forceinline__ float wave_max(float v) {
#pragma unroll
  for (int off = 32; off > 0; off >>= 1) v = fmaxf(v, __shfl_down(v, off, 64));
  return v;
}

// ---------------- weight ternary quant (i8) + per-row scale ----------------
// mask |w|>0.5*mean|w| invariant to row RMSNorm; ternary {-1,0,1} exact in i8.
// scale[o] = mean|w| * rsqrt(mean(w^2)+EPS) * row_scale[o]
__global__ __launch_bounds__(256) void wquant_kernel(
    const float* __restrict__ w, const float* __restrict__ row_scale,
    signed char* __restrict__ wq, float* __restrict__ scale, int K) {
  const int row = blockIdx.x;
  const int t = threadIdx.x;
  const float* wr = w + (size_t)row * K;
  float4 v0 = reinterpret_cast<const float4*>(wr)[2 * t];
  float4 v1 = reinterpret_cast<const float4*>(wr)[2 * t + 1];
  float f[8] = {v0.x, v0.y, v0.z, v0.w, v1.x, v1.y, v1.z, v1.w};
  float sa = 0.f, sq = 0.f;
#pragma unroll
  for (int i = 0; i < 8; ++i) { sa += fabsf(f[i]); sq += f[i] * f[i]; }
  sa = wave_sum(sa);
  sq = wave_sum(sq);
  __shared__ float smA[4], smQ[4];
  const int wid = t >> 6;
  if ((t & 63) == 0) { smA[wid] = sa; smQ[wid] = sq; }
  __syncthreads();
  const float sumabs = smA[0] + smA[1] + smA[2] + smA[3];
  const float sumsq  = smQ[0] + smQ[1] + smQ[2] + smQ[3];
  const float absmean = sumabs / (float)K;
  const float thr = 0.5f * absmean;
  union { signed char c[8]; uint2 u; } pk;
#pragma unroll
  for (int i = 0; i < 8; ++i)
    pk.c[i] = (fabsf(f[i]) > thr) ? (f[i] > 0.f ? (signed char)1 : (signed char)-1)
                                  : (signed char)0;
  reinterpret_cast<uint2*>(wq + (size_t)row * K)[t] = pk.u;
  if (t == 0)
    scale[row] = absmean * rsqrtf(sumsq / (float)K + EPSF) * row_scale[row];
}

// ---------------- input RMSNorm * g -> i8 (per-row symmetric) ----------------
__global__ __launch_bounds__(256) void xnorm_kernel(
    const float* __restrict__ x, const float* __restrict__ g,
    signed char* __restrict__ xq, float* __restrict__ sx, int K) {
  const int row = blockIdx.x;
  const int t = threadIdx.x;
  const float* xr = x + (size_t)row * K;
  float4 v0 = reinterpret_cast<const float4*>(xr)[2 * t];
  float4 v1 = reinterpret_cast<const float4*>(xr)[2 * t + 1];
  float f[8] = {v0.x, v0.y, v0.z, v0.w, v1.x, v1.y, v1.z, v1.w};
  float sq = 0.f;
#pragma unroll
  for (int i = 0; i < 8; ++i) sq += f[i] * f[i];
  sq = wave_sum(sq);
  __shared__ float smQ[4], smM[4];
  const int wid = t >> 6;
  if ((t & 63) == 0) smQ[wid] = sq;
  __syncthreads();
  const float sumsq = smQ[0] + smQ[1] + smQ[2] + smQ[3];
  const float rs = rsqrtf(sumsq / (float)K + EPSF);
  float4 g0 = reinterpret_cast<const float4*>(g)[2 * t];
  float4 g1 = reinterpret_cast<const float4*>(g)[2 * t + 1];
  float gg[8] = {g0.x, g0.y, g0.z, g0.w, g1.x, g1.y, g1.z, g1.w};
  float vv[8]; float am = 0.f;
#pragma unroll
  for (int i = 0; i < 8; ++i) {
    vv[i] = f[i] * rs * gg[i];
    am = fmaxf(am, fabsf(vv[i]));
  }
  am = wave_max(am);
  if ((t & 63) == 0) smM[wid] = am;
  __syncthreads();
  const float amax = fmaxf(fmaxf(smM[0], smM[1]), fmaxf(smM[2], smM[3]));
  const float inv = amax > 0.f ? 127.f / amax : 0.f;
  union { signed char c[8]; uint2 u; } pk;
#pragma unroll
  for (int i = 0; i < 8; ++i)
    pk.c[i] = (signed char)__float2int_rn(vv[i] * inv);
  reinterpret_cast<uint2*>(xq + (size_t)row * K)[t] = pk.u;
  if (t == 0) sx[row] = amax > 0.f ? amax / 127.f : 0.f;
}

// ---------------- i8 NT GEMM, 256x256 tile, 8-phase pipeline ----------------
// C[m,n] = sx[m]*scale[n]*sum_k qA[m,k]*t[n,k] + bias[n]; i32 dot is exact.
// 512 threads = 8 waves (2M x 4N); per-wave 128x64; BK=128 i8.
// ROUND-6 changes:
//  * XOR swizzle (R2's measured-zero-conflict pattern; round 5's additive
//    perm cost exactly 4 conflict-cycles per ds_read_b128 = 6.29e6 total):
//    stored slot for global granule G at lds row r is G ^ (r&7). All
//    fragment rows are ≡ fr (mod 8), so read slot = (s*4+kq) ^ (fr&7),
//    row-group independent -> ds_read offsets fold to immediates.
//    Staging source granule = (tid&7) ^ (sr&7) (valid for the +64-row
//    second load: 64&7 == 0). Both-sides-or-neither discipline kept.
//  * ONE barrier per phase (post-MFMA barrier removed). Safety: each
//    phase's ds_reads are lgkm-waited before that phase's MFMA (compiler
//    inserts the wait), which precedes the next barrier; every STAGE
//    writes a slot whose last readers completed >=1 barrier earlier
//    (min pair: S1@P1 writes A1h1, read at (j-1)P7 -> reads complete
//    before (j-1)P8's barrier, write issues after it). vmcnt FIFO is
//    per-wave, unchanged by barrier count.
// Steady-state vmcnt FIFO (loads; 1 stage = 2 gld_lds):
//  enter P1 with 8 {S5..S8}(j-1); P1 +S1=10, VM(6) drains S5,S6 (read
//  P2/P3); P4 +S2..S4=12, VM(8) drains S7,S8 (read P5); P5 +S5=10,
//  VM(6) drains S1,S2 (read P6/P7); P8 +S6..S8=12, VM(8) drains S3,S4
//  (read next P1). Peel: P1 VM(6) [10->6], P4 VM(4) [6->4], P5 VM(0).

#define BAR() do { __builtin_amdgcn_sched_barrier(0); \
                   asm volatile("" ::: "memory"); \
                   __builtin_amdgcn_s_barrier(); \
                   asm volatile("" ::: "memory"); \
                   __builtin_amdgcn_sched_barrier(0); } while (0)
#define VM(n) asm volatile("s_waitcnt vmcnt(" #n ")" ::: "memory")

__global__ __launch_bounds__(512, 2) void gemm_kernel(
    const signed char* __restrict__ A,   // [M][K] i8 (xq)
    const signed char* __restrict__ B,   // [N][K] i8 ternary (wq)
    const float* __restrict__ scale, const float* __restrict__ bias,
    const float* __restrict__ sx,
    float* __restrict__ C, int M, int N, int K) {
  __shared__ signed char lds[2][2][2][16384];

  const int tid  = threadIdx.x;
  const int lane = tid & 63;
  const int wid  = tid >> 6;
  const int wm   = wid >> 2;   // 0..1
  const int wn   = wid & 3;    // 0..3
  const int fr   = lane & 15;
  const int kq   = lane >> 4;

  // chunked XCD swizzle (round-2 mapping: all 8 bn co-resident per XCD)
  const int nwg = gridDim.x;
  const int cpx = nwg >> 3;
  const int swz = (blockIdx.x & 7) * cpx + (blockIdx.x >> 3);
  const int NBN = N >> 8;
  const int bn = swz % NBN;
  const int bm = swz / NBN;
  const int mBase = bm * 256, nBase = bn * 256;

  const size_t Kb = (size_t)K;  // bytes per row (i8)

  // ---- staging constants: thread t -> lds row sr=t>>3, granule slot t&7;
  // XOR-inverse source granule (same for +64-row second load: 64&7==0).
  const int sr = tid >> 3;                           // 0..63
  const int gsrc = (tid & 7) ^ (sr & 7);             // global granule
  const char* Abyte = (const char*)A + (size_t)(mBase + sr) * Kb + gsrc * 16;
  const char* Bbyte = (const char*)B +
      (size_t)(nBase + ((sr >> 5) * 64) + (sr & 31)) * Kb + gsrc * 16;

#define STAGE_A(bufi, h, t) do { \
    __builtin_amdgcn_global_load_lds( \
      (const __attribute__((address_space(1))) void*)(Abyte + (size_t)((h) * 64) * Kb + (size_t)(t) * 128), \
      (__attribute__((address_space(3))) void*)(&lds[bufi][0][h][tid * 16]), 16, 0, 0); \
    __builtin_amdgcn_global_load_lds( \
      (const __attribute__((address_space(1))) void*)(Abyte + (size_t)(128 + (h) * 64) * Kb + (size_t)(t) * 128), \
      (__attribute__((address_space(3))) void*)(&lds[bufi][0][h][8192 + tid * 16]), 16, 0, 0); \
  } while (0)

#define STAGE_B(bufi, h, t) do { \
    __builtin_amdgcn_global_load_lds( \
      (const __attribute__((address_space(1))) void*)(Bbyte + (size_t)((h) * 32) * Kb + (size_t)(t) * 128), \
      (__attribute__((address_space(3))) void*)(&lds[bufi][1][h][tid * 16]), 16, 0, 0); \
    __builtin_amdgcn_global_load_lds( \
      (const __attribute__((address_space(1))) void*)(Bbyte + (size_t)(128 + (h) * 32) * Kb + (size_t)(t) * 128), \
      (__attribute__((address_space(3))) void*)(&lds[bufi][1][h][8192 + tid * 16]), 16, 0, 0); \
  } while (0)

  // ---- reader constants (XOR perm on ds_read; row&7 == fr&7 always) ----
  const int slot0 = ((kq ^ (fr & 7)) << 4);   // byte offset, s=0 granule
  const int aRowB = (wm * 64 + fr) * 128;     // A lds row byte base
  const int bRowB = (wn * 32 + fr) * 128;     // B lds row byte base

  i32x4 aF[4][2], bF[4][2];
  i32x4 acc[8][4];
#pragma unroll
  for (int m = 0; m < 8; ++m)
#pragma unroll
    for (int n = 0; n < 4; ++n) acc[m][n] = (i32x4){0, 0, 0, 0};

#define LDA(bufi, mg) do { \
    _Pragma("unroll") for (int mm = 0; mm < 4; ++mm) \
    _Pragma("unroll") for (int s = 0; s < 2; ++s) \
      aF[mm][s] = *(const i32x4*)&lds[bufi][0][mg][ \
          aRowB + mm * 2048 + (slot0 ^ (s << 6))]; \
  } while (0)

#define LDB(bufi, np) do { \
    _Pragma("unroll") for (int nn = 0; nn < 2; ++nn) \
    _Pragma("unroll") for (int s = 0; s < 2; ++s) \
      bF[(np) * 2 + nn][s] = *(const i32x4*)&lds[bufi][1][np][ \
          bRowB + nn * 2048 + (slot0 ^ (s << 6))]; \
  } while (0)

#define MFMA_Q(mg, np) do { \
    __builtin_amdgcn_s_setprio(1); \
    _Pragma("unroll") for (int mm = 0; mm < 4; ++mm) \
    _Pragma("unroll") for (int nn = 0; nn < 2; ++nn) { \
      i32x4 c = acc[(mg) * 4 + mm][(np) * 2 + nn]; \
      c = __builtin_amdgcn_mfma_i32_16x16x64_i8(aF[mm][0], bF[(np) * 2 + nn][0], c, 0, 0, 0); \
      c = __builtin_amdgcn_mfma_i32_16x16x64_i8(aF[mm][1], bF[(np) * 2 + nn][1], c, 0, 0, 0); \
      acc[(mg) * 4 + mm][(np) * 2 + nn] = c; \
    } \
    __builtin_amdgcn_s_setprio(0); } while (0)

  const int crowBase = mBase + wm * 128 + kq * 4;
  const int ccolBase = nBase + wn * 64 + fr;

#define STORE_Q(mg, np) do { \
    float sxq_[4][4]; \
    _Pragma("unroll") for (int mm = 0; mm < 4; ++mm) \
    _Pragma("unroll") for (int r = 0; r < 4; ++r) \
      sxq_[mm][r] = sx[crowBase + ((mg) * 4 + mm) * 16 + r]; \
    _Pragma("unroll") for (int nn = 0; nn < 2; ++nn) { \
      const int gc = ccolBase + ((np) * 2 + nn) * 16; \
      const float sc = scale[gc]; \
      const float bi = bias[gc]; \
      _Pragma("unroll") for (int mm = 0; mm < 4; ++mm) { \
        const int r0 = crowBase + ((mg) * 4 + mm) * 16; \
        _Pragma("unroll") for (int r = 0; r < 4; ++r) \
          C[(size_t)(r0 + r) * (size_t)N + (size_t)gc] = \
              (float)acc[(mg) * 4 + mm][(np) * 2 + nn][r] * (sxq_[mm][r] * sc) + bi; \
      } } } while (0)

  // ---- prologue: tile0 complete, tile1 h0 halves ----
  STAGE_A(0, 0, 0); STAGE_B(0, 0, 0);
  STAGE_A(0, 1, 0); STAGE_B(0, 1, 0);
  STAGE_A(1, 0, 1); STAGE_B(1, 0, 1);
  VM(8);
  BAR();

  const int NT = K >> 7;  // 128-wide K-tiles; 2048/128 = 16; 7 iters + peel
  for (int i = 0; i < (NT >> 1) - 1; ++i) {
    const int t1  = 2 * i + 1;
    const int tn0 = 2 * i + 2;
    const int tn1 = 2 * i + 3;
    // P1
    LDA(0, 0); LDB(0, 0); STAGE_A(1, 1, t1); VM(6);
    BAR(); MFMA_Q(0, 0);
    // P2
    LDB(0, 1); STAGE_B(1, 1, t1);
    BAR(); MFMA_Q(0, 1);
    // P3
    LDA(0, 1); STAGE_A(0, 0, tn0);
    BAR(); MFMA_Q(1, 0);
    // P4
    STAGE_B(0, 0, tn0); VM(8);
    BAR(); MFMA_Q(1, 1);
    // P5
    LDA(1, 0); LDB(1, 0); STAGE_A(0, 1, tn0); VM(6);
    BAR(); MFMA_Q(0, 0);
    // P6
    LDB(1, 1); STAGE_B(0, 1, tn0);
    BAR(); MFMA_Q(0, 1);
    // P7
    LDA(1, 1); STAGE_A(1, 0, tn1);
    BAR(); MFMA_Q(1, 0);
    // P8
    STAGE_B(1, 0, tn1); VM(8);
    BAR(); MFMA_Q(1, 1);
  }

  // ---- peeled last iteration (tiles NT-2 in buf0, NT-1 in buf1) ----
  {
    const int tl = NT - 1;
    // P1: stage buf1 h1 (still needed by P6/P7)
    LDA(0, 0); LDB(0, 0); STAGE_A(1, 1, tl); VM(6);
    BAR(); MFMA_Q(0, 0);
    // P2
    LDB(0, 1); STAGE_B(1, 1, tl);
    BAR(); MFMA_Q(0, 1);
    // P3
    LDA(0, 1);
    BAR(); MFMA_Q(1, 0);
    // P4: drain buf1 h0 pair -> 2 stages left
    VM(4);
    BAR(); MFMA_Q(1, 1);
    // P5: drain remaining; quadrants final from here -> store inline
    LDA(1, 0); LDB(1, 0); VM(0);
    BAR(); MFMA_Q(0, 0); STORE_Q(0, 0);
    // P6
    LDB(1, 1);
    BAR(); MFMA_Q(0, 1); STORE_Q(0, 1);
    // P7
    LDA(1, 1);
    BAR(); MFMA_Q(1, 0); STORE_Q(1, 0);
    // P8
    BAR(); MFMA_Q(1, 1); STORE_Q(1, 1);
  }
#undef STAGE_A
#undef STAGE_B
#undef LDA
#undef LDB
#undef MFMA_Q
#undef STORE_Q
}

extern "C" void kernel_launch(void* const* d_in, const int* in_sizes, int n_in,
                              void* d_out, int out_size, void* d_ws, size_t ws_size,
                              hipStream_t stream) {
  const float* x         = (const float*)d_in[0];  // [B,S,Din]
  const float* weight    = (const float*)d_in[1];  // [Dout,Din]
  const float* row_scale = (const float*)d_in[2];  // [Dout,1]
  const float* bias      = (const float*)d_in[3];  // [Dout]
  const float* g         = (const float*)d_in[4];  // [Din]
  float* out = (float*)d_out;

  const int Din  = in_sizes[4];         // 2048
  const int Dout = in_sizes[3];         // 2048
  const int Mrows = in_sizes[0] / Din;  // 16384

  // ws: wq i8 [Dout*Din] | xq i8 [M*Din] | scale f32 [Dout] | sx f32 [M]
  char* ws = (char*)d_ws;
  signed char* wq = (signed char*)ws;
  signed char* xq = (signed char*)(ws + (size_t)Dout * Din);
  float* scale = (float*)(ws + (size_t)Dout * Din + (size_t)Mrows * Din);
  float* sx = scale + Dout;

  wquant_kernel<<<Dout, 256, 0, stream>>>(weight, row_scale, wq, scale, Din);
  xnorm_kernel<<<Mrows, 256, 0, stream>>>(x, g, xq, sx, Din);
  const int grid = (Mrows / 256) * (Dout / 256);
  gemm_kernel<<<grid, 512, 0, stream>>>(xq, wq, scale, bias, sx, out,
                                        Mrows, Dout, Din);
}